// Round 4
// baseline (671.204 us; speedup 1.0000x reference)
//
#include <hip/hip_runtime.h>
#include <hip/hip_bf16.h>
#include <math.h>
#include <stdint.h>

#define DIM   64
#define KNB   16
#define QKVW  192
#define H2PAD 272   // 256 + 16 elem: rows offset 32B in bank space (verified min-cycle)
#define KVPAD 144   // 128 + 16 elem

typedef short bf16x8 __attribute__((ext_vector_type(8)));
typedef float f32x4  __attribute__((ext_vector_type(4)));

__device__ __forceinline__ short f2bf_s(float x) {
    return (short)__builtin_bit_cast(unsigned short, __float2bfloat16(x));
}
__device__ __forceinline__ float bf2f(uint16_t u) {
    uint32_t v = ((uint32_t)u) << 16;
    return __builtin_bit_cast(float, v);
}

// ---------------------------------------------------------------------------
// qkv: 16 rows per block, x staged in LDS (read once), w_qkv L2-resident.
// q -> f32 [N][64]; k,v -> bf16 [N][128].
// ---------------------------------------------------------------------------
__global__ __launch_bounds__(256) void qkv_kernel(
    const float* __restrict__ x, const float* __restrict__ wqkv,
    float* __restrict__ qf, uint16_t* __restrict__ kvp, int n)
{
    const int tid = threadIdx.x;
    const int c   = tid & 63;
    const int rq  = tid >> 6;
    const int r0  = blockIdx.x * 16;
    __shared__ float s_x[16][64];
#pragma unroll
    for (int t = 0; t < 4; ++t) {
        const int row = r0 + rq + 4 * t;
        s_x[rq + 4 * t][c] = (row < n) ? x[(size_t)row * 64 + c] : 0.f;
    }
    __syncthreads();
    float aq[4] = {0, 0, 0, 0}, ak[4] = {0, 0, 0, 0}, av[4] = {0, 0, 0, 0};
    for (int d = 0; d < 64; ++d) {
        const float w0 = wqkv[d * QKVW + c];
        const float w1 = wqkv[d * QKVW + 64 + c];
        const float w2 = wqkv[d * QKVW + 128 + c];
#pragma unroll
        for (int t = 0; t < 4; ++t) {
            const float xv = s_x[rq + 4 * t][d];
            aq[t] = fmaf(xv, w0, aq[t]);
            ak[t] = fmaf(xv, w1, ak[t]);
            av[t] = fmaf(xv, w2, av[t]);
        }
    }
#pragma unroll
    for (int t = 0; t < 4; ++t) {
        const int row = r0 + rq + 4 * t;
        if (row < n) {
            qf[(size_t)row * 64 + c]           = aq[t];
            kvp[(size_t)row * 128 + c]         = (uint16_t)f2bf_s(ak[t]);
            kvp[(size_t)row * 128 + 64 + c]    = (uint16_t)f2bf_s(av[t]);
        }
    }
}

// ---------------------------------------------------------------------------
// Prepack am_w1 / am_w2 / pm_w2 into bf16 MFMA fragment order.
// Fragment: non-K = lane&15, K = 32*kt + 8*(lane>>4) + j.
// (A-frag of W^T == B-frag of W, so these packs serve both operand roles.)
// ---------------------------------------------------------------------------
__global__ __launch_bounds__(256) void wpack_kernel(
    const float* __restrict__ am_w1, const float* __restrict__ am_w2,
    const float* __restrict__ pm_w2,
    uint16_t* __restrict__ w1p, uint16_t* __restrict__ w2p, uint16_t* __restrict__ pw2p)
{
    int t = blockIdx.x * 256 + threadIdx.x;
    if (t >= 36864) return;
    int j = t & 7, lane = (t >> 3) & 63, tile = t >> 9;
    int g = lane >> 4, nb = lane & 15;
    if (tile < 32) {
        int mt = tile >> 1, kt = tile & 1;
        w1p[t] = (uint16_t)f2bf_s(am_w1[(32 * kt + 8 * g + j) * 256 + 16 * mt + nb]);
    } else if (tile < 64) {
        int tt = tile - 32;
        int mt = tt >> 3, kt = tt & 7;
        w2p[t - 16384] = (uint16_t)f2bf_s(am_w2[(32 * kt + 8 * g + j) * 64 + 16 * mt + nb]);
    } else {
        int tt = tile - 64;
        int nt = tt >> 1, kt = tt & 1;
        pw2p[t - 32768] = (uint16_t)f2bf_s(pm_w2[(32 * kt + 8 * g + j) * 64 + 16 * nt + nb]);
    }
}

// ---------------------------------------------------------------------------
// Main. 4 waves/block, grid-stride, weights register-resident.
// Score MFMA is operand-swapped so D = [neighbor][channel]: softmax needs
// only 6 shuffles and rel stays in registers for the aggregation.
// LDS per point: s_rel (rel - q, swizzled), s_h2 / s_kv (row-padded +32B).
// 2 barriers per point; all tiles double-buffered.
// ---------------------------------------------------------------------------
__global__ __launch_bounds__(256, 4) void ptl_main(
    const float* __restrict__ pos,
    const int* __restrict__ aidx,
    const uint8_t* __restrict__ mask,
    const float* __restrict__ pm_w1,
    const float* __restrict__ pm_b1,
    const float* __restrict__ pm_b2,
    const float* __restrict__ am_b1,
    const float* __restrict__ qf,
    const uint16_t* __restrict__ kvp,
    const uint16_t* __restrict__ w1p,
    const uint16_t* __restrict__ w2p,
    const uint16_t* __restrict__ pw2p,
    float* __restrict__ out,
    int npts)
{
    const int tid  = threadIdx.x;
    const int w    = tid >> 6;
    const int lane = tid & 63;
    const int g    = lane >> 4;
    const int nb   = lane & 15;
    const int swz_nb = 16 * (nb & 7);

    __shared__ alignas(16) float    s_rel[2][1024];          // 16 x 64 f32, XOR-swizzled
    __shared__ alignas(16) uint16_t s_h2[2][16 * H2PAD];     // [neighbor][256+pad] bf16
    __shared__ alignas(16) uint16_t s_kv[2][16 * KVPAD];     // [neighbor][128+pad] bf16

    // register-resident weight fragments (72 VGPR)
    bf16x8 aw1[4][2], aw2[8], bpw2[2];
#pragma unroll
    for (int m = 0; m < 4; ++m)
#pragma unroll
        for (int kt = 0; kt < 2; ++kt)
            aw1[m][kt] = *(const bf16x8*)(w1p + (size_t)(((4 * w + m) * 2 + kt) * 64 + lane) * 8);
#pragma unroll
    for (int kt = 0; kt < 8; ++kt)
        aw2[kt] = *(const bf16x8*)(w2p + (size_t)((w * 8 + kt) * 64 + lane) * 8);
#pragma unroll
    for (int kt = 0; kt < 2; ++kt)
        bpw2[kt] = *(const bf16x8*)(pw2p + (size_t)((w * 2 + kt) * 64 + lane) * 8);

    const int srow = tid >> 4, schunk = tid & 15;   // kv staging assignment
    const int relw_byte0 = 4 * (16 * w + nb);       // rel write column byte

    int buf = 0;
    for (int i = blockIdx.x; i < npts; i += gridDim.x, buf ^= 1) {
        // ---- cooperative kv stage: 16 neighbor rows x 256B, 16B/thread ----
        {
            const int sidx = aidx[i * KNB + srow];
            const uint4 d4 = *(const uint4*)(kvp + (size_t)sidx * 128 + schunk * 8);
            *(uint4*)&s_kv[buf][srow * KVPAD + schunk * 8] = d4;
        }

        const int nidx = aidx[i * KNB + nb];
        const float px = pos[3 * i], py = pos[3 * i + 1], pz = pos[3 * i + 2];
        const float rx = pos[3 * nidx]     - px;
        const float ry = pos[3 * nidx + 1] - py;
        const float rz = pos[3 * nidx + 2] - pz;

        // ---- pos-MLP layer 1 -> h1 A-frags (neighbor nb, hidden 32kt+8g+j) ----
        bf16x8 h1f[2];
#pragma unroll
        for (int kt = 0; kt < 2; ++kt) {
            const int hb = 32 * kt + 8 * g;
            float w0[8], w1r[8], w2r[8], bb[8];
            *(float4*)&w0[0]  = *(const float4*)(pm_w1 + hb);
            *(float4*)&w0[4]  = *(const float4*)(pm_w1 + hb + 4);
            *(float4*)&w1r[0] = *(const float4*)(pm_w1 + 64 + hb);
            *(float4*)&w1r[4] = *(const float4*)(pm_w1 + 64 + hb + 4);
            *(float4*)&w2r[0] = *(const float4*)(pm_w1 + 128 + hb);
            *(float4*)&w2r[4] = *(const float4*)(pm_w1 + 128 + hb + 4);
            *(float4*)&bb[0]  = *(const float4*)(pm_b1 + hb);
            *(float4*)&bb[4]  = *(const float4*)(pm_b1 + hb + 4);
            bf16x8 f;
#pragma unroll
            for (int jj = 0; jj < 8; ++jj) {
                float v = fmaf(rx, w0[jj], fmaf(ry, w1r[jj], fmaf(rz, w2r[jj], bb[jj])));
                f[jj] = f2bf_s(fmaxf(v, 0.f));
            }
            h1f[kt] = f;
        }

        // ---- rel: D = [neighbor 4g+r][channel 16w+nb]; keep for agg ----
        f32x4 racc = {0.f, 0.f, 0.f, 0.f};
        racc = __builtin_amdgcn_mfma_f32_16x16x32_bf16(h1f[0], bpw2[0], racc, 0, 0, 0);
        racc = __builtin_amdgcn_mfma_f32_16x16x32_bf16(h1f[1], bpw2[1], racc, 0, 0, 0);
        const float pb2 = pm_b2[16 * w + nb];
        const float qc  = qf[(size_t)i * 64 + 16 * w + nb];
        f32x4 relagg;
#pragma unroll
        for (int r = 0; r < 4; ++r) {
            relagg[r] = racc[r] + pb2;
            const int row = 4 * g + r;
            *(float*)((char*)&s_rel[buf][0] + row * 256 + (relw_byte0 ^ (16 * (row & 7)))) =
                relagg[r] - qc;   // rel' = rel - q folded here
        }
        __syncthreads();

        // ---- t = k + rel' -> B-frags (neighbor nb, channel 32kt+8g+j) ----
        bf16x8 tf[2];
#pragma unroll
        for (int kt = 0; kt < 2; ++kt) {
            const bf16x8 k8 = *(const bf16x8*)&s_kv[buf][nb * KVPAD + 32 * kt + 8 * g];
            const float4 rl0 = *(const float4*)((const char*)&s_rel[buf][0] + nb * 256 + ((128 * kt + 32 * g) ^ swz_nb));
            const float4 rl1 = *(const float4*)((const char*)&s_rel[buf][0] + nb * 256 + ((128 * kt + 32 * g + 16) ^ swz_nb));
            const float rv[8] = {rl0.x, rl0.y, rl0.z, rl0.w, rl1.x, rl1.y, rl1.z, rl1.w};
            bf16x8 f;
#pragma unroll
            for (int jj = 0; jj < 8; ++jj)
                f[jj] = f2bf_s(bf2f((uint16_t)k8[jj]) + rv[jj]);
            tf[kt] = f;
        }

        // ---- step5: h2[neighbor][hidden] slices, wave w owns hidden 64w.. ----
        f32x4 hacc[4];
#pragma unroll
        for (int m = 0; m < 4; ++m) {
            f32x4 a = {0.f, 0.f, 0.f, 0.f};
            a = __builtin_amdgcn_mfma_f32_16x16x32_bf16(aw1[m][0], tf[0], a, 0, 0, 0);
            a = __builtin_amdgcn_mfma_f32_16x16x32_bf16(aw1[m][1], tf[1], a, 0, 0, 0);
            hacc[m] = a;
        }
#pragma unroll
        for (int m = 0; m < 4; ++m) {
            const int hb = 16 * (4 * w + m) + 4 * g;
            const float4 b4 = *(const float4*)(am_b1 + hb);
            const uint32_t lo = (uint32_t)(uint16_t)f2bf_s(fmaxf(hacc[m][0] + b4.x, 0.f))
                              | ((uint32_t)(uint16_t)f2bf_s(fmaxf(hacc[m][1] + b4.y, 0.f)) << 16);
            const uint32_t hi = (uint32_t)(uint16_t)f2bf_s(fmaxf(hacc[m][2] + b4.z, 0.f))
                              | ((uint32_t)(uint16_t)f2bf_s(fmaxf(hacc[m][3] + b4.w, 0.f)) << 16);
            *(uint2*)&s_h2[buf][nb * H2PAD + hb] = make_uint2(lo, hi);
        }
        __syncthreads();

        // ---- scores (SWAPPED): D = h2 @ w2 -> [neighbor 4g+r][channel 16w+nb] ----
        f32x4 wacc = {0.f, 0.f, 0.f, 0.f};
#pragma unroll
        for (int kt = 0; kt < 8; ++kt) {
            const bf16x8 bh2 = *(const bf16x8*)&s_h2[buf][nb * H2PAD + 32 * kt + 8 * g];
            wacc = __builtin_amdgcn_mfma_f32_16x16x32_bf16(bh2, aw2[kt], wacc, 0, 0, 0);
        }

        // ---- softmax over neighbors: in-lane 4 + shfl over g (2 stages) ----
        const uchar4 m4 = *(const uchar4*)(mask + (size_t)i * KNB + 4 * g);
        float sc0 = m4.x ? -INFINITY : wacc[0];
        float sc1 = m4.y ? -INFINITY : wacc[1];
        float sc2 = m4.z ? -INFINITY : wacc[2];
        float sc3 = m4.w ? -INFINITY : wacc[3];
        float mx = fmaxf(fmaxf(sc0, sc1), fmaxf(sc2, sc3));
        mx = fmaxf(mx, __shfl_xor(mx, 16));
        mx = fmaxf(mx, __shfl_xor(mx, 32));
        const float e0 = __expf(sc0 - mx), e1 = __expf(sc1 - mx);
        const float e2 = __expf(sc2 - mx), e3 = __expf(sc3 - mx);
        float den = (e0 + e1) + (e2 + e3);

        // numerator: e * (v + rel), v from staged LDS, rel from registers
        const int vcol = 64 + 16 * w + nb;
        float num;
        {
            const float v0 = bf2f(s_kv[buf][(4 * g + 0) * KVPAD + vcol]);
            const float v1 = bf2f(s_kv[buf][(4 * g + 1) * KVPAD + vcol]);
            const float v2 = bf2f(s_kv[buf][(4 * g + 2) * KVPAD + vcol]);
            const float v3 = bf2f(s_kv[buf][(4 * g + 3) * KVPAD + vcol]);
            num = e0 * (v0 + relagg[0]);
            num = fmaf(e1, v1 + relagg[1], num);
            num = fmaf(e2, v2 + relagg[2], num);
            num = fmaf(e3, v3 + relagg[3], num);
        }
        den += __shfl_xor(den, 16); den += __shfl_xor(den, 32);
        num += __shfl_xor(num, 16); num += __shfl_xor(num, 32);
        if (lane < 16)
            out[(size_t)i * 64 + 16 * w + nb] = __fdividef(num, den);
    }
}

// ---------------------------------------------------------------------------
extern "C" void kernel_launch(void* const* d_in, const int* in_sizes, int n_in,
                              void* d_out, int out_size, void* d_ws, size_t ws_size,
                              hipStream_t stream) {
    const float*   x     = (const float*)d_in[0];
    const float*   pos   = (const float*)d_in[1];
    const int*     aidx  = (const int*)d_in[2];
    const uint8_t* mask  = (const uint8_t*)d_in[3];
    const float*   wqkv  = (const float*)d_in[4];
    const float*   pm_w1 = (const float*)d_in[5];
    const float*   pm_b1 = (const float*)d_in[6];
    const float*   pm_w2 = (const float*)d_in[7];
    const float*   pm_b2 = (const float*)d_in[8];
    const float*   am_w1 = (const float*)d_in[9];
    const float*   am_b1 = (const float*)d_in[10];
    const float*   am_w2 = (const float*)d_in[11];
    // am_b2 (d_in[12]) is constant over the softmax axis -> cancels, unused
    float* out = (float*)d_out;
    const int n = in_sizes[0] / DIM;

    uint8_t* ws = (uint8_t*)d_ws;
    float*    qf   = (float*)ws;                                  // n*64 f32
    uint16_t* kvp  = (uint16_t*)(ws + (size_t)n * 256);           // n*128 bf16
    uint16_t* w1p  = (uint16_t*)(ws + (size_t)n * 512);           // 16384 bf16
    uint16_t* w2p  = w1p + 16384;                                 // 16384 bf16
    uint16_t* pw2p = w2p + 16384;                                 // 4096 bf16

    qkv_kernel<<<(n + 15) / 16, 256, 0, stream>>>(x, wqkv, qf, kvp, n);
    wpack_kernel<<<144, 256, 0, stream>>>(am_w1, am_w2, pm_w2, w1p, w2p, pw2p);
    ptl_main<<<1024, 256, 0, stream>>>(pos, aidx, mask, pm_w1, pm_b1, pm_b2, am_b1,
                                       qf, kvp, w1p, w2p, pw2p, out, n);
}

// Round 5
// 238.539 us; speedup vs baseline: 2.8138x; 2.8138x over previous
//
#include <hip/hip_runtime.h>
#include <hip/hip_bf16.h>
#include <math.h>
#include <stdint.h>

#define DIM   64
#define KNB   16
#define QKVW  192
#define H2PAD 272   // 256 + 16 elem: rows offset 32B in bank space
#define KVPAD 144   // 128 + 16 elem

typedef short bf16x8 __attribute__((ext_vector_type(8)));
typedef float f32x4  __attribute__((ext_vector_type(4)));

__device__ __forceinline__ short f2bf_s(float x) {
    return (short)__builtin_bit_cast(unsigned short, __float2bfloat16(x));
}
__device__ __forceinline__ float bf2f(uint16_t u) {
    uint32_t v = ((uint32_t)u) << 16;
    return __builtin_bit_cast(float, v);
}

// ---------------------------------------------------------------------------
// qkv: 16 rows per block, x staged in LDS, w_qkv L2-resident.
// q -> f32 [N][64]; k,v -> bf16 [N][128].
// ---------------------------------------------------------------------------
__global__ __launch_bounds__(256) void qkv_kernel(
    const float* __restrict__ x, const float* __restrict__ wqkv,
    float* __restrict__ qf, uint16_t* __restrict__ kvp, int n)
{
    const int tid = threadIdx.x;
    const int c   = tid & 63;
    const int rq  = tid >> 6;
    const int r0  = blockIdx.x * 16;
    __shared__ float s_x[16][64];
#pragma unroll
    for (int t = 0; t < 4; ++t) {
        const int row = r0 + rq + 4 * t;
        s_x[rq + 4 * t][c] = (row < n) ? x[(size_t)row * 64 + c] : 0.f;
    }
    __syncthreads();
    float aq[4] = {0, 0, 0, 0}, ak[4] = {0, 0, 0, 0}, av[4] = {0, 0, 0, 0};
    for (int d = 0; d < 64; ++d) {
        const float w0 = wqkv[d * QKVW + c];
        const float w1 = wqkv[d * QKVW + 64 + c];
        const float w2 = wqkv[d * QKVW + 128 + c];
#pragma unroll
        for (int t = 0; t < 4; ++t) {
            const float xv = s_x[rq + 4 * t][d];
            aq[t] = fmaf(xv, w0, aq[t]);
            ak[t] = fmaf(xv, w1, ak[t]);
            av[t] = fmaf(xv, w2, av[t]);
        }
    }
#pragma unroll
    for (int t = 0; t < 4; ++t) {
        const int row = r0 + rq + 4 * t;
        if (row < n) {
            qf[(size_t)row * 64 + c]           = aq[t];
            kvp[(size_t)row * 128 + c]         = (uint16_t)f2bf_s(ak[t]);
            kvp[(size_t)row * 128 + 64 + c]    = (uint16_t)f2bf_s(av[t]);
        }
    }
}

// ---------------------------------------------------------------------------
// Prepack am_w1 / am_w2 / pm_w2 into bf16 MFMA fragment order.
// Fragment: non-K = lane&15, K = 32*kt + 8*(lane>>4) + j.
// (A-frag of W^T == B-frag of W, so these packs serve both operand roles.)
// ---------------------------------------------------------------------------
__global__ __launch_bounds__(256) void wpack_kernel(
    const float* __restrict__ am_w1, const float* __restrict__ am_w2,
    const float* __restrict__ pm_w2,
    uint16_t* __restrict__ w1p, uint16_t* __restrict__ w2p, uint16_t* __restrict__ pw2p)
{
    int t = blockIdx.x * 256 + threadIdx.x;
    if (t >= 36864) return;
    int j = t & 7, lane = (t >> 3) & 63, tile = t >> 9;
    int g = lane >> 4, nb = lane & 15;
    if (tile < 32) {
        int mt = tile >> 1, kt = tile & 1;
        w1p[t] = (uint16_t)f2bf_s(am_w1[(32 * kt + 8 * g + j) * 256 + 16 * mt + nb]);
    } else if (tile < 64) {
        int tt = tile - 32;
        int mt = tt >> 3, kt = tt & 7;
        w2p[t - 16384] = (uint16_t)f2bf_s(am_w2[(32 * kt + 8 * g + j) * 64 + 16 * mt + nb]);
    } else {
        int tt = tile - 64;
        int nt = tt >> 1, kt = tt & 1;
        pw2p[t - 32768] = (uint16_t)f2bf_s(pm_w2[(32 * kt + 8 * g + j) * 64 + 16 * nt + nb]);
    }
}

// ---------------------------------------------------------------------------
// Main. 4 waves/block, grid-stride, weights register-resident.
// launch_bounds (256,2): empirically gives 128 VGPR, no spill; with grid=1024
// the hardware still packs 4 blocks/CU (VGPR=128 cap, LDS 34.8KB*4 < 160KB).
// Score MFMA operand-swapped so D = [neighbor][channel]: 6-shuffle softmax,
// rel stays in registers for aggregation. 2 barriers/point, double-buffered.
// ---------------------------------------------------------------------------
__global__ __launch_bounds__(256, 2) void ptl_main(
    const float* __restrict__ pos,
    const int* __restrict__ aidx,
    const uint8_t* __restrict__ mask,
    const float* __restrict__ pm_w1,
    const float* __restrict__ pm_b1,
    const float* __restrict__ pm_b2,
    const float* __restrict__ am_b1,
    const float* __restrict__ qf,
    const uint16_t* __restrict__ kvp,
    const uint16_t* __restrict__ w1p,
    const uint16_t* __restrict__ w2p,
    const uint16_t* __restrict__ pw2p,
    float* __restrict__ out,
    int npts)
{
    const int tid  = threadIdx.x;
    const int w    = tid >> 6;
    const int lane = tid & 63;
    const int g    = lane >> 4;
    const int nb   = lane & 15;
    const int swz_nb = 16 * (nb & 7);

    __shared__ alignas(16) float    s_rel[2][1024];          // 16 x 64 f32, XOR-swizzled
    __shared__ alignas(16) uint16_t s_h2[2][16 * H2PAD];     // [neighbor][256+pad] bf16
    __shared__ alignas(16) uint16_t s_kv[2][16 * KVPAD];     // [neighbor][128+pad] bf16

    // register-resident weight fragments (72 VGPR)
    bf16x8 aw1[4][2], aw2[8], bpw2[2];
#pragma unroll
    for (int m = 0; m < 4; ++m)
#pragma unroll
        for (int kt = 0; kt < 2; ++kt)
            aw1[m][kt] = *(const bf16x8*)(w1p + (size_t)(((4 * w + m) * 2 + kt) * 64 + lane) * 8);
#pragma unroll
    for (int kt = 0; kt < 8; ++kt)
        aw2[kt] = *(const bf16x8*)(w2p + (size_t)((w * 8 + kt) * 64 + lane) * 8);
#pragma unroll
    for (int kt = 0; kt < 2; ++kt)
        bpw2[kt] = *(const bf16x8*)(pw2p + (size_t)((w * 2 + kt) * 64 + lane) * 8);

    const int srow = tid >> 4, schunk = tid & 15;   // kv staging assignment
    const int relw_byte0 = 4 * (16 * w + nb);       // rel write column byte

    int buf = 0;
    for (int i = blockIdx.x; i < npts; i += gridDim.x, buf ^= 1) {
        // ---- cooperative kv stage: 16 neighbor rows x 256B, 16B/thread ----
        {
            const int sidx = aidx[i * KNB + srow];
            const uint4 d4 = *(const uint4*)(kvp + (size_t)sidx * 128 + schunk * 8);
            *(uint4*)&s_kv[buf][srow * KVPAD + schunk * 8] = d4;
        }

        const int nidx = aidx[i * KNB + nb];
        const float px = pos[3 * i], py = pos[3 * i + 1], pz = pos[3 * i + 2];
        const float rx = pos[3 * nidx]     - px;
        const float ry = pos[3 * nidx + 1] - py;
        const float rz = pos[3 * nidx + 2] - pz;

        // ---- pos-MLP layer 1 -> h1 A-frags (neighbor nb, hidden 32kt+8g+j) ----
        bf16x8 h1f[2];
#pragma unroll
        for (int kt = 0; kt < 2; ++kt) {
            const int hb = 32 * kt + 8 * g;
            float w0[8], w1r[8], w2r[8], bb[8];
            *(float4*)&w0[0]  = *(const float4*)(pm_w1 + hb);
            *(float4*)&w0[4]  = *(const float4*)(pm_w1 + hb + 4);
            *(float4*)&w1r[0] = *(const float4*)(pm_w1 + 64 + hb);
            *(float4*)&w1r[4] = *(const float4*)(pm_w1 + 64 + hb + 4);
            *(float4*)&w2r[0] = *(const float4*)(pm_w1 + 128 + hb);
            *(float4*)&w2r[4] = *(const float4*)(pm_w1 + 128 + hb + 4);
            *(float4*)&bb[0]  = *(const float4*)(pm_b1 + hb);
            *(float4*)&bb[4]  = *(const float4*)(pm_b1 + hb + 4);
            bf16x8 f;
#pragma unroll
            for (int jj = 0; jj < 8; ++jj) {
                float v = fmaf(rx, w0[jj], fmaf(ry, w1r[jj], fmaf(rz, w2r[jj], bb[jj])));
                f[jj] = f2bf_s(fmaxf(v, 0.f));
            }
            h1f[kt] = f;
        }

        // ---- rel: D = [neighbor 4g+r][channel 16w+nb]; keep for agg ----
        f32x4 racc = {0.f, 0.f, 0.f, 0.f};
        racc = __builtin_amdgcn_mfma_f32_16x16x32_bf16(h1f[0], bpw2[0], racc, 0, 0, 0);
        racc = __builtin_amdgcn_mfma_f32_16x16x32_bf16(h1f[1], bpw2[1], racc, 0, 0, 0);
        const float pb2 = pm_b2[16 * w + nb];
        const float qc  = qf[(size_t)i * 64 + 16 * w + nb];
        f32x4 relagg;
#pragma unroll
        for (int r = 0; r < 4; ++r) {
            relagg[r] = racc[r] + pb2;
            const int row = 4 * g + r;
            *(float*)((char*)&s_rel[buf][0] + row * 256 + (relw_byte0 ^ (16 * (row & 7)))) =
                relagg[r] - qc;   // rel' = rel - q folded here
        }
        __syncthreads();

        // ---- t = k + rel' -> B-frags (neighbor nb, channel 32kt+8g+j) ----
        bf16x8 tf[2];
#pragma unroll
        for (int kt = 0; kt < 2; ++kt) {
            const bf16x8 k8 = *(const bf16x8*)&s_kv[buf][nb * KVPAD + 32 * kt + 8 * g];
            const float4 rl0 = *(const float4*)((const char*)&s_rel[buf][0] + nb * 256 + ((128 * kt + 32 * g) ^ swz_nb));
            const float4 rl1 = *(const float4*)((const char*)&s_rel[buf][0] + nb * 256 + ((128 * kt + 32 * g + 16) ^ swz_nb));
            const float rv[8] = {rl0.x, rl0.y, rl0.z, rl0.w, rl1.x, rl1.y, rl1.z, rl1.w};
            bf16x8 f;
#pragma unroll
            for (int jj = 0; jj < 8; ++jj)
                f[jj] = f2bf_s(bf2f((uint16_t)k8[jj]) + rv[jj]);
            tf[kt] = f;
        }

        // ---- step5: h2[neighbor][hidden] slices, wave w owns hidden 64w.. ----
        f32x4 hacc[4];
#pragma unroll
        for (int m = 0; m < 4; ++m) {
            f32x4 a = {0.f, 0.f, 0.f, 0.f};
            a = __builtin_amdgcn_mfma_f32_16x16x32_bf16(aw1[m][0], tf[0], a, 0, 0, 0);
            a = __builtin_amdgcn_mfma_f32_16x16x32_bf16(aw1[m][1], tf[1], a, 0, 0, 0);
            hacc[m] = a;
        }
#pragma unroll
        for (int m = 0; m < 4; ++m) {
            const int hb = 16 * (4 * w + m) + 4 * g;
            const float4 b4 = *(const float4*)(am_b1 + hb);
            const uint32_t lo = (uint32_t)(uint16_t)f2bf_s(fmaxf(hacc[m][0] + b4.x, 0.f))
                              | ((uint32_t)(uint16_t)f2bf_s(fmaxf(hacc[m][1] + b4.y, 0.f)) << 16);
            const uint32_t hi = (uint32_t)(uint16_t)f2bf_s(fmaxf(hacc[m][2] + b4.z, 0.f))
                              | ((uint32_t)(uint16_t)f2bf_s(fmaxf(hacc[m][3] + b4.w, 0.f)) << 16);
            *(uint2*)&s_h2[buf][nb * H2PAD + hb] = make_uint2(lo, hi);
        }
        __syncthreads();

        // ---- scores (SWAPPED): D = h2 @ w2 -> [neighbor 4g+r][channel 16w+nb] ----
        f32x4 wacc = {0.f, 0.f, 0.f, 0.f};
#pragma unroll
        for (int kt = 0; kt < 8; ++kt) {
            const bf16x8 bh2 = *(const bf16x8*)&s_h2[buf][nb * H2PAD + 32 * kt + 8 * g];
            wacc = __builtin_amdgcn_mfma_f32_16x16x32_bf16(bh2, aw2[kt], wacc, 0, 0, 0);
        }

        // ---- softmax over neighbors: in-lane 4 + shfl over g (2 stages) ----
        const uchar4 m4 = *(const uchar4*)(mask + (size_t)i * KNB + 4 * g);
        float sc0 = m4.x ? -INFINITY : wacc[0];
        float sc1 = m4.y ? -INFINITY : wacc[1];
        float sc2 = m4.z ? -INFINITY : wacc[2];
        float sc3 = m4.w ? -INFINITY : wacc[3];
        float mx = fmaxf(fmaxf(sc0, sc1), fmaxf(sc2, sc3));
        mx = fmaxf(mx, __shfl_xor(mx, 16));
        mx = fmaxf(mx, __shfl_xor(mx, 32));
        const float e0 = __expf(sc0 - mx), e1 = __expf(sc1 - mx);
        const float e2 = __expf(sc2 - mx), e3 = __expf(sc3 - mx);
        float den = (e0 + e1) + (e2 + e3);

        // numerator: e * (v + rel), v from staged LDS, rel from registers
        const int vcol = 64 + 16 * w + nb;
        float num;
        {
            const float v0 = bf2f(s_kv[buf][(4 * g + 0) * KVPAD + vcol]);
            const float v1 = bf2f(s_kv[buf][(4 * g + 1) * KVPAD + vcol]);
            const float v2 = bf2f(s_kv[buf][(4 * g + 2) * KVPAD + vcol]);
            const float v3 = bf2f(s_kv[buf][(4 * g + 3) * KVPAD + vcol]);
            num = e0 * (v0 + relagg[0]);
            num = fmaf(e1, v1 + relagg[1], num);
            num = fmaf(e2, v2 + relagg[2], num);
            num = fmaf(e3, v3 + relagg[3], num);
        }
        den += __shfl_xor(den, 16); den += __shfl_xor(den, 32);
        num += __shfl_xor(num, 16); num += __shfl_xor(num, 32);
        if (lane < 16)
            out[(size_t)i * 64 + 16 * w + nb] = __fdividef(num, den);
    }
}

// ---------------------------------------------------------------------------
extern "C" void kernel_launch(void* const* d_in, const int* in_sizes, int n_in,
                              void* d_out, int out_size, void* d_ws, size_t ws_size,
                              hipStream_t stream) {
    const float*   x     = (const float*)d_in[0];
    const float*   pos   = (const float*)d_in[1];
    const int*     aidx  = (const int*)d_in[2];
    const uint8_t* mask  = (const uint8_t*)d_in[3];
    const float*   wqkv  = (const float*)d_in[4];
    const float*   pm_w1 = (const float*)d_in[5];
    const float*   pm_b1 = (const float*)d_in[6];
    const float*   pm_w2 = (const float*)d_in[7];
    const float*   pm_b2 = (const float*)d_in[8];
    const float*   am_w1 = (const float*)d_in[9];
    const float*   am_b1 = (const float*)d_in[10];
    const float*   am_w2 = (const float*)d_in[11];
    // am_b2 (d_in[12]) is constant over the softmax axis -> cancels, unused
    float* out = (float*)d_out;
    const int n = in_sizes[0] / DIM;

    uint8_t* ws = (uint8_t*)d_ws;
    float*    qf   = (float*)ws;                                  // n*64 f32
    uint16_t* kvp  = (uint16_t*)(ws + (size_t)n * 256);           // n*128 bf16
    uint16_t* w1p  = (uint16_t*)(ws + (size_t)n * 512);           // 16384 bf16
    uint16_t* w2p  = w1p + 16384;                                 // 16384 bf16
    uint16_t* pw2p = w2p + 16384;                                 // 4096 bf16

    qkv_kernel<<<(n + 15) / 16, 256, 0, stream>>>(x, wqkv, qf, kvp, n);
    wpack_kernel<<<144, 256, 0, stream>>>(am_w1, am_w2, pm_w2, w1p, w2p, pw2p);
    ptl_main<<<1024, 256, 0, stream>>>(pos, aidx, mask, pm_w1, pm_b1, pm_b2, am_b1,
                                       qf, kvp, w1p, w2p, pw2p, out, n);
}